// Round 8
// baseline (3105.765 us; speedup 1.0000x reference)
//
#include <hip/hip_runtime.h>

#define TT 2048

typedef _Float16 f16;
typedef _Float16 f16x2 __attribute__((ext_vector_type(2)));
typedef _Float16 f16x8 __attribute__((ext_vector_type(8)));
typedef float f32x4 __attribute__((ext_vector_type(4)));
typedef unsigned int u32;

static __device__ __forceinline__ u32 packh2(float a, float b) {
  f16x2 v; v[0] = (f16)a; v[1] = (f16)b;
  return __builtin_bit_cast(u32, v);
}
static __device__ __forceinline__ uint4 pack8(float4 a, float4 b) {
  uint4 r;
  r.x = packh2(a.x, a.y); r.y = packh2(a.z, a.w);
  r.z = packh2(b.x, b.y); r.w = packh2(b.z, b.w);
  return r;
}
static __device__ __forceinline__ float sigm(float x) {
  return 1.f / (1.f + __expf(-x));
}
static __device__ __forceinline__ float tanh_(float x) {
  x = fminf(15.f, fmaxf(-15.f, x));
  const float e = __expf(2.f * x);
  return (e - 1.f) / (e + 1.f);
}
// B-fragment for mfma_f32_16x16x32_f16 from row-major W[rows][ld] (f32):
// lane holds B[k][n]=W[G+(l&15)][kbase + i], i=0..7 (8 consecutive k).
static __device__ __forceinline__ f16x8 ldwfrag(const float* __restrict__ W,
                                                int row, int ld, int kbase) {
  const float* p = W + row * ld + kbase;
  const float4 a = *(const float4*)p;
  const float4 b = *(const float4*)(p + 4);
  f16x8 r;
  r[0]=(f16)a.x; r[1]=(f16)a.y; r[2]=(f16)a.z; r[3]=(f16)a.w;
  r[4]=(f16)b.x; r[5]=(f16)b.y; r[6]=(f16)b.z; r[7]=(f16)b.w;
  return r;
}
static __device__ __forceinline__ f32x4 MF(f16x8 a, f16x8 b, f32x4 c) {
  return __builtin_amdgcn_mfma_f32_16x16x32_f16(a, b, c, 0, 0, 0);
}

// MFMA persistent LSTM. One block = 16 batch rows, 7 waves:
//   waves 0-3: layer-1. Wave w owns units [16w,16w+16): 4 N-tiles (i,f,g,o at
//     gate cols 64q+16w). D layout (n=lane&15, m=(lane>>4)*4+reg) puts
//     i,f,g,o for (row,unit) in-lane -> lane-local cell update, c1 in 4 regs.
//   waves 4-5: layer-2, one step behind (pipeline skew as R4).
//   wave 6: x staging f32->f16 into LDS ring (A-frag layout), loads batched
//     4 steps to amortize the barrier's vmcnt(0) drain.
// Weights are per-wave MFMA B-fragments (8 f16/lane each): if the allocator
// parks them in AGPRs, MFMA reads AGPRs natively -> the R3-R7 weight-
// residency pathology is structurally harmless here.
__launch_bounds__(448, 1)
__global__ void lstm2_mfma_kernel(const float* __restrict__ x1,
                                  const float* __restrict__ x2,
                                  const float* __restrict__ Wih1,
                                  const float* __restrict__ Whh1,
                                  const float* __restrict__ bih1,
                                  const float* __restrict__ bhh1,
                                  const float* __restrict__ Wih2,
                                  const float* __restrict__ Whh2,
                                  const float* __restrict__ bih2,
                                  const float* __restrict__ bhh2,
                                  float* __restrict__ out)
{
  // x ring: [slot][c][kgroup][m] 16B groups; slot = step&7, 2KB/slot
  __shared__ __align__(16) u32 s_ring[8][512];
  __shared__ __align__(16) f16 s_h1[2][16][72];   // [buf][row][unit], pad 72
  __shared__ __align__(16) f16 s_h2[2][16][40];   // [buf][row][unit], pad 40

  const int tid = threadIdx.x;
  const int l = tid & 63;
  const int wid = tid >> 6;        // 0-3 L1, 4-5 L2, 6 x-stage
  const int ln = l & 15;           // n (gate col) / m (row) index
  const int lg = l >> 4;           // k-group 0..3
  const int bid = blockIdx.x;      // 32 blocks
  const int which = bid >> 4;      // 0 -> x1, 1 -> x2
  const int rowbase = (bid & 15) * 16;

  // ---- zero-init h1[-1], h2[-1] buffers (slot 1) ----
  for (int idx = tid; idx < 16 * 72; idx += 448) ((f16*)s_h1[1])[idx] = (f16)0.f;
  for (int idx = tid; idx < 16 * 40; idx += 448) ((f16*)s_h2[1])[idx] = (f16)0.f;

  // ---- per-wave weight fragments ----
  f16x8 wx[4][2];   // L1: Wih1 tiles | L2: Wih2 tiles
  f16x8 wh[4][2];   // L1: Whh1 tiles | L2: Whh2 tiles (chunk 0 only)
  float bs[4] = {0.f, 0.f, 0.f, 0.f};
  #pragma unroll
  for (int q = 0; q < 4; ++q) { wx[q][0] = wx[q][1] = wh[q][0] = wh[q][1] = (f16x8)(f16)0.f; }

  if (wid < 4) {
    #pragma unroll
    for (int q = 0; q < 4; ++q) {
      const int g = 64 * q + 16 * wid + ln;
      #pragma unroll
      for (int c = 0; c < 2; ++c) {
        wx[q][c] = ldwfrag(Wih1, g, 64, 32 * c + lg * 8);
        wh[q][c] = ldwfrag(Whh1, g, 64, 32 * c + lg * 8);
      }
      bs[q] = bih1[g] + bhh1[g];
    }
  } else if (wid < 6) {
    const int w2 = wid - 4;
    #pragma unroll
    for (int q = 0; q < 4; ++q) {
      const int g = 32 * q + 16 * w2 + ln;
      #pragma unroll
      for (int c = 0; c < 2; ++c) wx[q][c] = ldwfrag(Wih2, g, 64, 32 * c + lg * 8);
      wh[q][0] = ldwfrag(Whh2, g, 32, lg * 8);
      bs[q] = bih2[g] + bhh2[g];
    }
  }

  // unit column this lane owns (L1: 16*wid+ln; L2: 16*(wid-4)+ln)
  const int uu = 16 * ((wid < 4) ? wid : (wid - 4)) + ln;
  float cc[4] = {0.f, 0.f, 0.f, 0.f};   // c1 (L1 waves) / c2 (L2 waves)

  // ---- x-stage prologue (wave 6): slots 0,1 + prime batch (steps 2..5) ----
  float4 xb[4][4];
  uint4 u4[4][2];
  const float* __restrict__ xrow =
      (which ? x2 : x1) + (size_t)(rowbase + ln) * (TT * 64);
  if (wid == 6) {
    #pragma unroll
    for (int p = 0; p < 2; ++p) {
      const float* ps = xrow + p * 64;
      const float4 a0 = *(const float4*)(ps + lg * 8);
      const float4 a1 = *(const float4*)(ps + lg * 8 + 4);
      const float4 b0 = *(const float4*)(ps + 32 + lg * 8);
      const float4 b1 = *(const float4*)(ps + 32 + lg * 8 + 4);
      *(uint4*)&s_ring[p][lg * 64 + ln * 4] = pack8(a0, a1);
      *(uint4*)&s_ring[p][256 + lg * 64 + ln * 4] = pack8(b0, b1);
    }
    #pragma unroll
    for (int b = 0; b < 4; ++b) {
      const float* ps = xrow + (2 + b) * 64;
      xb[b][0] = *(const float4*)(ps + lg * 8);
      xb[b][1] = *(const float4*)(ps + lg * 8 + 4);
      xb[b][2] = *(const float4*)(ps + 32 + lg * 8);
      xb[b][3] = *(const float4*)(ps + 32 + lg * 8 + 4);
    }
  }
  __syncthreads();

  #pragma unroll 1
  for (int ii = 0; ii <= TT; ii += 4) {
    #pragma unroll
    for (int r = 0; r < 4; ++r) {
      const int i = ii + r;
      if (wid < 4) {
        // ---- layer-1 step i ----
        if (i < TT) {
          const u32* rs = s_ring[i & 7];
          const f16x8 xa0 = *(const f16x8*)&rs[lg * 64 + ln * 4];
          const f16x8 xa1 = *(const f16x8*)&rs[256 + lg * 64 + ln * 4];
          const f16* hb = &s_h1[(i + 1) & 1][ln][lg * 8];   // h1[i-1]
          const f16x8 ha0 = *(const f16x8*)hb;
          const f16x8 ha1 = *(const f16x8*)(hb + 32);
          f32x4 a0 = {bs[0], bs[0], bs[0], bs[0]};
          f32x4 a1 = {bs[1], bs[1], bs[1], bs[1]};
          f32x4 a2 = {bs[2], bs[2], bs[2], bs[2]};
          f32x4 a3 = {bs[3], bs[3], bs[3], bs[3]};
          a0 = MF(xa0, wx[0][0], a0); a1 = MF(xa0, wx[1][0], a1);
          a2 = MF(xa0, wx[2][0], a2); a3 = MF(xa0, wx[3][0], a3);
          a0 = MF(xa1, wx[0][1], a0); a1 = MF(xa1, wx[1][1], a1);
          a2 = MF(xa1, wx[2][1], a2); a3 = MF(xa1, wx[3][1], a3);
          a0 = MF(ha0, wh[0][0], a0); a1 = MF(ha0, wh[1][0], a1);
          a2 = MF(ha0, wh[2][0], a2); a3 = MF(ha0, wh[3][0], a3);
          a0 = MF(ha1, wh[0][1], a0); a1 = MF(ha1, wh[1][1], a1);
          a2 = MF(ha1, wh[2][1], a2); a3 = MF(ha1, wh[3][1], a3);
          #pragma unroll
          for (int r2 = 0; r2 < 4; ++r2) {
            const float gi = sigm(a0[r2]), gf = sigm(a1[r2]);
            const float gg = tanh_(a2[r2]), go = sigm(a3[r2]);
            cc[r2] = gf * cc[r2] + gi * gg;
            const float hv = go * tanh_(cc[r2]);
            s_h1[i & 1][lg * 4 + r2][uu] = (f16)hv;
          }
        }
      } else if (wid < 6) {
        // ---- layer-2 step t = i-1 ----
        if (i >= 1 && i <= TT) {
          const int t = i - 1;
          const f16* hb = &s_h1[t & 1][ln][lg * 8];         // h1[t]
          const f16x8 ha0 = *(const f16x8*)hb;
          const f16x8 ha1 = *(const f16x8*)(hb + 32);
          const f16x8 g0 = *(const f16x8*)&s_h2[(t + 1) & 1][ln][lg * 8]; // h2[t-1]
          f32x4 b0 = {bs[0], bs[0], bs[0], bs[0]};
          f32x4 b1 = {bs[1], bs[1], bs[1], bs[1]};
          f32x4 b2 = {bs[2], bs[2], bs[2], bs[2]};
          f32x4 b3 = {bs[3], bs[3], bs[3], bs[3]};
          b0 = MF(ha0, wx[0][0], b0); b1 = MF(ha0, wx[1][0], b1);
          b2 = MF(ha0, wx[2][0], b2); b3 = MF(ha0, wx[3][0], b3);
          b0 = MF(ha1, wx[0][1], b0); b1 = MF(ha1, wx[1][1], b1);
          b2 = MF(ha1, wx[2][1], b2); b3 = MF(ha1, wx[3][1], b3);
          b0 = MF(g0, wh[0][0], b0);  b1 = MF(g0, wh[1][0], b1);
          b2 = MF(g0, wh[2][0], b2);  b3 = MF(g0, wh[3][0], b3);
          #pragma unroll
          for (int r2 = 0; r2 < 4; ++r2) {
            const float gi = sigm(b0[r2]), gf = sigm(b1[r2]);
            const float gg = tanh_(b2[r2]), go = sigm(b3[r2]);
            cc[r2] = gf * cc[r2] + gi * gg;
            const float hv = go * tanh_(cc[r2]);
            s_h2[t & 1][lg * 4 + r2][uu] = (f16)hv;
            if (t == TT - 1)
              out[which * 8192 + (rowbase + lg * 4 + r2) * 32 + uu] = hv;
          }
        }
      } else {
        // ---- x staging (wave 6) ----
        if (r == 0) {
          // convert previous batch (steps ii+2..ii+5), loaded 4 iters ago
          #pragma unroll
          for (int b = 0; b < 4; ++b) {
            u4[b][0] = pack8(xb[b][0], xb[b][1]);
            u4[b][1] = pack8(xb[b][2], xb[b][3]);
          }
          // issue next batch: steps ii+6..ii+9 (clamped; clamped unused)
          #pragma unroll
          for (int b = 0; b < 4; ++b) {
            int s = ii + 6 + b; if (s > TT - 1) s = TT - 1;
            const float* ps = xrow + s * 64;
            xb[b][0] = *(const float4*)(ps + lg * 8);
            xb[b][1] = *(const float4*)(ps + lg * 8 + 4);
            xb[b][2] = *(const float4*)(ps + 32 + lg * 8);
            xb[b][3] = *(const float4*)(ps + 32 + lg * 8 + 4);
          }
        }
        if (i + 2 < TT) {
          u32* rd = s_ring[(i + 2) & 7];
          *(uint4*)&rd[lg * 64 + ln * 4] = u4[r][0];
          *(uint4*)&rd[256 + lg * 64 + ln * 4] = u4[r][1];
        }
      }
      __syncthreads();
    }
  }
}

extern "C" void kernel_launch(void* const* d_in, const int* in_sizes, int n_in,
                              void* d_out, int out_size, void* d_ws, size_t ws_size,
                              hipStream_t stream) {
  const float* x1   = (const float*)d_in[0];
  const float* x2   = (const float*)d_in[1];
  const float* Wih1 = (const float*)d_in[2];
  const float* Whh1 = (const float*)d_in[3];
  const float* bih1 = (const float*)d_in[4];
  const float* bhh1 = (const float*)d_in[5];
  const float* Wih2 = (const float*)d_in[6];
  const float* Whh2 = (const float*)d_in[7];
  const float* bih2 = (const float*)d_in[8];
  const float* bhh2 = (const float*)d_in[9];
  float* out = (float*)d_out;

  lstm2_mfma_kernel<<<dim3(32), dim3(448), 0, stream>>>(
      x1, x2, Wih1, Whh1, bih1, bhh1, Wih2, Whh2, bih2, bhh2, out);
}